// Round 10
// baseline (237.099 us; speedup 1.0000x reference)
//
#include <hip/hip_runtime.h>

#define S_DEPTH 256
#define NRES 384
#define CIN 32
#define CZ 128
#define MDIM (NRES * CIN) /* 12288 */

typedef short bf16x8 __attribute__((ext_vector_type(8)));
typedef short short4v __attribute__((ext_vector_type(4)));
typedef float f32x4 __attribute__((ext_vector_type(4)));

static __device__ __forceinline__ unsigned short f2bf(float f) {
  unsigned int u = __float_as_uint(f);
  unsigned int r = (u + 0x7fffu + ((u >> 16) & 1u)) >> 16; // RNE
  return (unsigned short)r;
}

static __device__ __forceinline__ void gld16(const void* g, void* l) {
  __builtin_amdgcn_global_load_lds((__attribute__((address_space(1))) void*)(g),
                                   (__attribute__((address_space(3))) void*)(l),
                                   16, 0, 0);
}

// ---------------- k_pre v4 (R8, measured ~2-4us; single launch) -------------
__global__ __launch_bounds__(256) void k_pre(
    const float* __restrict__ mm, const float* __restrict__ gamma,
    const float* __restrict__ beta, const float* __restrict__ W1,
    const float* __restrict__ W2, const float* __restrict__ W3,
    unsigned short* __restrict__ aT, unsigned short* __restrict__ bT,
    unsigned short* __restrict__ W3T) {
  __shared__ __align__(16) char sraw[256 * 33 * 4];      // f32 LN buf [256][33]
  __shared__ __align__(16) char mn_raw[256 * 80];        // bf16 mn, row stride 80B
  const int t = threadIdx.x;

  if (blockIdx.x < 16) {
    unsigned short (*tile)[72] = (unsigned short(*)[72])sraw; // [128][72]
    const int b = blockIdx.x;
    const int d0 = (b & 7) * 4;
    const int e0 = (b >> 3) * 64;
#pragma unroll
    for (int iter = 0; iter < 32; ++iter) {
      int lr_ = iter * 4 + (t >> 6);
      int c = lr_ >> 2, dl = lr_ & 3;
      int q = c * 32 + d0 + dl;
      tile[lr_][t & 63] = f2bf(W3[q * 128 + e0 + (t & 63)]);
    }
    __syncthreads();
    const int e_l = t >> 2;
    const int dl = t & 3;
    unsigned short* dst = W3T + (((size_t)(d0 + dl) * 128) + e0 + e_l) * 32;
#pragma unroll
    for (int j = 0; j < 32; ++j) dst[j] = tile[j * 4 + dl][e_l];
    return;
  }

  float* buf = (float*)sraw; // [256][33]
  const int i = blockIdx.x - 16;

#pragma unroll
  for (int it = 0; it < 8; ++it) {
    int s = it * 32 + (t >> 3);
    int c4 = (t & 7) * 4;
    const float4 v = *(const float4*)(mm + ((size_t)s * NRES + i) * CIN + c4);
    buf[s * 33 + c4 + 0] = v.x;
    buf[s * 33 + c4 + 1] = v.y;
    buf[s * 33 + c4 + 2] = v.z;
    buf[s * 33 + c4 + 3] = v.w;
  }
  __syncthreads();

  {
    float x[32];
#pragma unroll
    for (int k = 0; k < 32; ++k) x[k] = buf[t * 33 + k];
    float mu = 0.f;
#pragma unroll
    for (int k = 0; k < 32; ++k) mu += x[k];
    mu *= (1.f / 32.f);
    float var = 0.f;
#pragma unroll
    for (int k = 0; k < 32; ++k) {
      float dk = x[k] - mu;
      var += dk * dk;
    }
    var *= (1.f / 32.f);
    float inv = rsqrtf(var + 1e-5f);
    char* row = mn_raw + t * 80;
#pragma unroll
    for (int q = 0; q < 4; ++q) {
      bf16x8 pk;
#pragma unroll
      for (int j = 0; j < 8; ++j) {
        int k = q * 8 + j;
        pk[j] = (short)f2bf((x[k] - mu) * inv * gamma[k] + beta[k]);
      }
      *(bf16x8*)(row + q * 16) = pk;
    }
  }

  const int l = t & 63;
  const int w = t >> 6;       // wave = s-slice of 64 rows
  const int lr = l & 15;
  const int quad = l >> 4;

  bf16x8 wfr[4];
#pragma unroll
  for (int nf = 0; nf < 4; ++nf) {
    const float* W = (nf < 2) ? W1 : W2;
    const int c = lr + (nf & 1) * 16;
#pragma unroll
    for (int j = 0; j < 8; ++j)
      wfr[nf][j] = (short)f2bf(W[(quad * 8 + j) * 32 + c]);
  }

  __syncthreads();

  f32x4 acc2[4][4];
#pragma unroll
  for (int sg = 0; sg < 4; ++sg) {
    const bf16x8 mfrag =
        *(const bf16x8*)(mn_raw + (size_t)(w * 64 + sg * 16 + lr) * 80 + quad * 16);
#pragma unroll
    for (int nf = 0; nf < 4; ++nf) {
      f32x4 z = {0.f, 0.f, 0.f, 0.f};
      acc2[sg][nf] = __builtin_amdgcn_mfma_f32_16x16x32_bf16(wfr[nf], mfrag, z, 0, 0, 0);
    }
  }

  const size_t rowbase = (size_t)w * MDIM + (size_t)i * 32;
#pragma unroll
  for (int sg = 0; sg < 4; ++sg)
#pragma unroll
    for (int nf = 0; nf < 4; ++nf) {
      unsigned short* tgt = (nf < 2) ? aT : bT;
      const int c0 = (nf & 1) * 16 + quad * 4;
      const int s = sg * 16 + lr;
#pragma unroll
      for (int r = 0; r < 4; ++r)
        tgt[(rowbase + c0 + r) * 64 + s] = f2bf(acc2[sg][nf][r]);
    }
}

// ---------------- kernel 2: R4 main + P2xE4 epilogue at R0 reg footprint ----
// R9 theory (resubmitted after broker timeout): R3(+28us)/R6(+29us)
// regressions were SPILLS, not traffic -- VGPR_Count pinned at 124 in all
// variants (allocator clamped at the 2-waves/SIMD 256-reg boundary;
// acc[8][4]=128 AGPR + 124 VGPR). R3's ring-4 added 32 regs, R6's zacc[4][4]
// added 48 -> silent scratch. This variant: R3's P=2(p) x E=4(e) epilogue
// shape (halves o_lds reads, 512KB/blk) with depth-1 W3T prefetch: epi regs
// = aef[2](8) + 2x(wcur+wnxt)(16) = 24 = EXACTLY R0's footprint.
__global__ __launch_bounds__(512, 2) void k_opm(
    const unsigned short* __restrict__ aT, const unsigned short* __restrict__ bT,
    const unsigned short* __restrict__ W3T, const float* __restrict__ b3,
    float* __restrict__ out) {
  __shared__ __align__(16) char smem[131072]; // 2x(A32K+B32K) staging; o_lds 128KB
  const int t = threadIdx.x;
  const int w = t >> 6;  // wave 0..7
  const int l = t & 63;
  const int lr = l & 15;
  const int quad = l >> 4;
  const int wm = w >> 2, wn = w & 3;

  const int g = blockIdx.x;
  const int xcd = g & 7;
  const int rr = g >> 3;                   // 0..287
  const int bx = rr / 6;                   // 0..47
  const int by = xcd * 6 + (rr - bx * 6);  // 0..47
  const int m0 = by * 256;
  const int n0 = bx * 256;

  f32x4 acc[8][4];
#pragma unroll
  for (int mt = 0; mt < 8; ++mt)
#pragma unroll
    for (int nt = 0; nt < 4; ++nt) {
      acc[mt][nt][0] = 0.f; acc[mt][nt][1] = 0.f;
      acc[mt][nt][2] = 0.f; acc[mt][nt][3] = 0.f;
    }

  // lane offset inside a 1KB chunk (8 rows x 128B), XOR k-seg swizzle
  const int laneoff = (l >> 3) * 64 + (((l & 7) ^ (l >> 3)) * 8);
  const int r8 = lr & 7;

  // ---- 2-phase pipelined main loop over 4 k-slices of 64 (R4 verified) ----
  {
    const unsigned short* aS = aT + (size_t)m0 * 64;
    const unsigned short* bS = bT + (size_t)n0 * 64;
#pragma unroll
    for (int p_ = 0; p_ < 4; ++p_) {
      int ch = p_ * 8 + w;
      gld16(aS + ch * 512 + laneoff, smem + ch * 1024);
      gld16(bS + ch * 512 + laneoff, smem + 32768 + ch * 1024);
    }
  }
  __syncthreads();

  for (int kt = 0; kt < 4; ++kt) {
    if (kt < 3) {  // issue next-slice loads into the other buffer
      char* nb = smem + ((kt + 1) & 1) * 65536;
      const unsigned short* aS = aT + ((size_t)(kt + 1) * MDIM + m0) * 64;
      const unsigned short* bS = bT + ((size_t)(kt + 1) * MDIM + n0) * 64;
#pragma unroll
      for (int p_ = 0; p_ < 4; ++p_) {
        int ch = p_ * 8 + w;
        gld16(aS + ch * 512 + laneoff, nb + ch * 1024);
        gld16(bS + ch * 512 + laneoff, nb + 32768 + ch * 1024);
      }
    }
    const char* cb = smem + (kt & 1) * 65536;
    const char* cbB = cb + 32768;

#pragma unroll
    for (int ks = 0; ks < 2; ++ks) {
      const int segoff = (((ks * 4 + quad) ^ r8) << 4);
      bf16x8 af[8];
#pragma unroll
      for (int mt = 0; mt < 8; ++mt) {
        int chunk = wm * 16 + mt * 2 + (lr >> 3);
        af[mt] = *(const bf16x8*)(cb + chunk * 1024 + r8 * 128 + segoff);
      }
#pragma unroll
      for (int nt = 0; nt < 4; ++nt) {
        int chunk = wn * 8 + nt * 2 + (lr >> 3);
        bf16x8 bfr = *(const bf16x8*)(cbB + chunk * 1024 + r8 * 128 + segoff);
#pragma unroll
        for (int mt = 0; mt < 8; ++mt)
          acc[mt][nt] =
              __builtin_amdgcn_mfma_f32_16x16x32_bf16(af[mt], bfr, acc[mt][nt], 0, 0, 0);
      }
    }
    __syncthreads();  // next-tile DMA has the full compute phase to land
  }

  // ---- repack o (bf16, /256) into o_lds[64 p][1024 q'] XOR-swizzled ----
  const float scale = 1.0f / 256.0f;
#pragma unroll
  for (int mt = 0; mt < 8; ++mt) {
    int i_l = wm * 4 + (mt >> 1);
    int chc = 2 * (mt & 1) + (quad >> 1); // c0>>3, c0 = (mt&1)*16 + quad*4
#pragma unroll
    for (int nt = 0; nt < 4; ++nt) {
      int j_l = wn * 2 + (nt >> 1);
      int d = (nt & 1) * 16 + lr;
      int p = i_l * 8 + j_l;
      int ch = d * 4 + chc;
      int key = (p ^ d) & 7;
      int off = p * 2048 + ((ch ^ key) << 4) + 8 * (quad & 1);
      short4v pk;
      pk[0] = (short)f2bf(acc[mt][nt][0] * scale);
      pk[1] = (short)f2bf(acc[mt][nt][1] * scale);
      pk[2] = (short)f2bf(acc[mt][nt][2] * scale);
      pk[3] = (short)f2bf(acc[mt][nt][3] * scale);
      *(short4v*)(smem + off) = pk;
    }
  }
  __syncthreads();

  // ---- epilogue: wave (pb = w>>2, eb = w&3): rows pb*32..+32, e-cols
  //      eb*32..+32 (two 16-wide tiles). Depth-1 W3T prefetch, 2 streams.
  const int pb = w >> 2;  // 0..1
  const int eb = w & 3;   // 0..3
  f32x4 zacc[2][2];
#pragma unroll
  for (int a = 0; a < 2; ++a)
#pragma unroll
    for (int e_ = 0; e_ < 2; ++e_) {
      zacc[a][e_][0] = 0.f; zacc[a][e_][1] = 0.f;
      zacc[a][e_][2] = 0.f; zacc[a][e_][3] = 0.f;
    }
  const float bias0 = b3[eb * 32 + lr];
  const float bias1 = b3[eb * 32 + 16 + lr];

  // kq-major W3T: frag = W3T + (kq*128 + e)*32 + quad*8 ; kq step 4096 shorts
  const unsigned short* wg0 = W3T + (size_t)(eb * 32 + lr) * 32 + quad * 8;
  const unsigned short* wg1 = wg0 + 512; // e + 16

  bf16x8 wc0 = *(const bf16x8*)(wg0);
  bf16x8 wc1 = *(const bf16x8*)(wg1);
#pragma unroll
  for (int kq = 0; kq < 32; ++kq) {
    bf16x8 wn0, wn1;
    if (kq < 31) {
      wn0 = *(const bf16x8*)(wg0 + (size_t)(kq + 1) * 4096);
      wn1 = *(const bf16x8*)(wg1 + (size_t)(kq + 1) * 4096);
    }
    bf16x8 aef[2];
#pragma unroll
    for (int mte = 0; mte < 2; ++mte) {
      int row_ = pb * 32 + mte * 16 + lr;
      int ch = kq * 4 + quad;
      int key = (row_ ^ kq) & 7;
      aef[mte] = *(const bf16x8*)(smem + row_ * 2048 + ((ch ^ key) << 4));
    }
#pragma unroll
    for (int mte = 0; mte < 2; ++mte) {
      zacc[mte][0] =
          __builtin_amdgcn_mfma_f32_16x16x32_bf16(aef[mte], wc0, zacc[mte][0], 0, 0, 0);
      zacc[mte][1] =
          __builtin_amdgcn_mfma_f32_16x16x32_bf16(aef[mte], wc1, zacc[mte][1], 0, 0, 0);
    }
    wc0 = wn0; wc1 = wn1;
  }

  const int i0 = by * 8, j0 = bx * 8;
#pragma unroll
  for (int mte = 0; mte < 2; ++mte)
#pragma unroll
    for (int r = 0; r < 4; ++r) {
      int p = pb * 32 + mte * 16 + quad * 4 + r;
      size_t base = (((size_t)(i0 + (p >> 3))) * NRES + (j0 + (p & 7))) * CZ;
      out[base + eb * 32 + lr] = zacc[mte][0][r] + bias0;
      out[base + eb * 32 + 16 + lr] = zacc[mte][1][r] + bias1;
    }
}

// ---------------- host launch ----------------
extern "C" void kernel_launch(void* const* d_in, const int* in_sizes, int n_in,
                              void* d_out, int out_size, void* d_ws, size_t ws_size,
                              hipStream_t stream) {
  const float* m = (const float*)d_in[0];
  const float* gamma = (const float*)d_in[1];
  const float* beta = (const float*)d_in[2];
  const float* W1 = (const float*)d_in[3];
  const float* W2 = (const float*)d_in[4];
  const float* W3 = (const float*)d_in[5];
  const float* b3 = (const float*)d_in[6];
  float* out = (float*)d_out;

  unsigned short* aT = (unsigned short*)d_ws;                 // k-slice-major
  unsigned short* bT = aT + (size_t)MDIM * S_DEPTH;
  unsigned short* W3T = bT + (size_t)MDIM * S_DEPTH;          // kq-major

  k_pre<<<400, 256, 0, stream>>>(m, gamma, beta, W1, W2, W3, aT, bT, W3T);
  k_opm<<<2304, 512, 0, stream>>>(aT, bT, W3T, b3, out);
}

// Round 11
// 208.853 us; speedup vs baseline: 1.1352x; 1.1352x over previous
//
#include <hip/hip_runtime.h>

#define S_DEPTH 256
#define NRES 384
#define CIN 32
#define CZ 128
#define MDIM (NRES * CIN) /* 12288 */

typedef short bf16x8 __attribute__((ext_vector_type(8)));
typedef short short4v __attribute__((ext_vector_type(4)));
typedef float f32x4 __attribute__((ext_vector_type(4)));

static __device__ __forceinline__ unsigned short f2bf(float f) {
  unsigned int u = __float_as_uint(f);
  unsigned int r = (u + 0x7fffu + ((u >> 16) & 1u)) >> 16; // RNE
  return (unsigned short)r;
}

static __device__ __forceinline__ void gld16(const void* g, void* l) {
  __builtin_amdgcn_global_load_lds((__attribute__((address_space(1))) void*)(g),
                                   (__attribute__((address_space(3))) void*)(l),
                                   16, 0, 0);
}

// ---------------- k_pre v4 (R8-verified; ~2-4us; single launch) -------------
// MFMA LN+proj, swapped operands: D[col=lr]=s -> lane-contiguous b16 stores.
__global__ __launch_bounds__(256) void k_pre(
    const float* __restrict__ mm, const float* __restrict__ gamma,
    const float* __restrict__ beta, const float* __restrict__ W1,
    const float* __restrict__ W2, const float* __restrict__ W3,
    unsigned short* __restrict__ aT, unsigned short* __restrict__ bT,
    unsigned short* __restrict__ W3T) {
  __shared__ __align__(16) char sraw[256 * 33 * 4];      // f32 LN buf [256][33]
  __shared__ __align__(16) char mn_raw[256 * 80];        // bf16 mn, row stride 80B
  const int t = threadIdx.x;

  if (blockIdx.x < 16) {
    unsigned short (*tile)[72] = (unsigned short(*)[72])sraw; // [128][72]
    const int b = blockIdx.x;
    const int d0 = (b & 7) * 4;
    const int e0 = (b >> 3) * 64;
#pragma unroll
    for (int iter = 0; iter < 32; ++iter) {
      int lr_ = iter * 4 + (t >> 6);
      int c = lr_ >> 2, dl = lr_ & 3;
      int q = c * 32 + d0 + dl;
      tile[lr_][t & 63] = f2bf(W3[q * 128 + e0 + (t & 63)]);
    }
    __syncthreads();
    const int e_l = t >> 2;
    const int dl = t & 3;
    unsigned short* dst = W3T + (((size_t)(d0 + dl) * 128) + e0 + e_l) * 32;
#pragma unroll
    for (int j = 0; j < 32; ++j) dst[j] = tile[j * 4 + dl][e_l];
    return;
  }

  float* buf = (float*)sraw; // [256][33]
  const int i = blockIdx.x - 16;

#pragma unroll
  for (int it = 0; it < 8; ++it) {
    int s = it * 32 + (t >> 3);
    int c4 = (t & 7) * 4;
    const float4 v = *(const float4*)(mm + ((size_t)s * NRES + i) * CIN + c4);
    buf[s * 33 + c4 + 0] = v.x;
    buf[s * 33 + c4 + 1] = v.y;
    buf[s * 33 + c4 + 2] = v.z;
    buf[s * 33 + c4 + 3] = v.w;
  }
  __syncthreads();

  {
    float x[32];
#pragma unroll
    for (int k = 0; k < 32; ++k) x[k] = buf[t * 33 + k];
    float mu = 0.f;
#pragma unroll
    for (int k = 0; k < 32; ++k) mu += x[k];
    mu *= (1.f / 32.f);
    float var = 0.f;
#pragma unroll
    for (int k = 0; k < 32; ++k) {
      float dk = x[k] - mu;
      var += dk * dk;
    }
    var *= (1.f / 32.f);
    float inv = rsqrtf(var + 1e-5f);
    char* row = mn_raw + t * 80;
#pragma unroll
    for (int q = 0; q < 4; ++q) {
      bf16x8 pk;
#pragma unroll
      for (int j = 0; j < 8; ++j) {
        int k = q * 8 + j;
        pk[j] = (short)f2bf((x[k] - mu) * inv * gamma[k] + beta[k]);
      }
      *(bf16x8*)(row + q * 16) = pk;
    }
  }

  const int l = t & 63;
  const int w = t >> 6;       // wave = s-slice of 64 rows
  const int lr = l & 15;
  const int quad = l >> 4;

  bf16x8 wfr[4];
#pragma unroll
  for (int nf = 0; nf < 4; ++nf) {
    const float* W = (nf < 2) ? W1 : W2;
    const int c = lr + (nf & 1) * 16;
#pragma unroll
    for (int j = 0; j < 8; ++j)
      wfr[nf][j] = (short)f2bf(W[(quad * 8 + j) * 32 + c]);
  }

  __syncthreads();

  f32x4 acc2[4][4];
#pragma unroll
  for (int sg = 0; sg < 4; ++sg) {
    const bf16x8 mfrag =
        *(const bf16x8*)(mn_raw + (size_t)(w * 64 + sg * 16 + lr) * 80 + quad * 16);
#pragma unroll
    for (int nf = 0; nf < 4; ++nf) {
      f32x4 z = {0.f, 0.f, 0.f, 0.f};
      acc2[sg][nf] = __builtin_amdgcn_mfma_f32_16x16x32_bf16(wfr[nf], mfrag, z, 0, 0, 0);
    }
  }

  const size_t rowbase = (size_t)w * MDIM + (size_t)i * 32;
#pragma unroll
  for (int sg = 0; sg < 4; ++sg)
#pragma unroll
    for (int nf = 0; nf < 4; ++nf) {
      unsigned short* tgt = (nf < 2) ? aT : bT;
      const int c0 = (nf & 1) * 16 + quad * 4;
      const int s = sg * 16 + lr;
#pragma unroll
      for (int r = 0; r < 4; ++r)
        tgt[(rowbase + c0 + r) * 64 + s] = f2bf(acc2[sg][nf][r]);
    }
}

// ---------------- kernel 2: EXACT R4 k_opm (136.8us, verified 3x) -----------
// Session ledger for the epilogue (all A/B'd): 1x8 e-split + depth-1 W3T
// prefetch beats P2xE4 (+26us: R3/R10, indep. of regs/prefetch), kq-split
// partials (+29us: R6), ring-4 (null: R2). The 1-global+4-ds+4-MFMA per-kq
// interleave with 4 indep acc chains is the schedule optimum found.
// Main loop: dbuf 2-phase (-10us vs 3-sync, R2-vs-R3 A/B).
__global__ __launch_bounds__(512, 2) void k_opm(
    const unsigned short* __restrict__ aT, const unsigned short* __restrict__ bT,
    const unsigned short* __restrict__ W3T, const float* __restrict__ b3,
    float* __restrict__ out) {
  __shared__ __align__(16) char smem[131072]; // 2x(A32K+B32K) staging; o_lds 128KB
  const int t = threadIdx.x;
  const int w = t >> 6;  // wave 0..7
  const int l = t & 63;
  const int lr = l & 15;
  const int quad = l >> 4;
  const int wm = w >> 2, wn = w & 3;

  const int g = blockIdx.x;
  const int xcd = g & 7;
  const int rr = g >> 3;                   // 0..287
  const int bx = rr / 6;                   // 0..47
  const int by = xcd * 6 + (rr - bx * 6);  // 0..47
  const int m0 = by * 256;
  const int n0 = bx * 256;

  f32x4 acc[8][4];
#pragma unroll
  for (int mt = 0; mt < 8; ++mt)
#pragma unroll
    for (int nt = 0; nt < 4; ++nt) {
      acc[mt][nt][0] = 0.f; acc[mt][nt][1] = 0.f;
      acc[mt][nt][2] = 0.f; acc[mt][nt][3] = 0.f;
    }

  // lane offset inside a 1KB chunk (8 rows x 128B), XOR k-seg swizzle
  const int laneoff = (l >> 3) * 64 + (((l & 7) ^ (l >> 3)) * 8);
  const int r8 = lr & 7;

  // ---- 2-phase pipelined main loop over 4 k-slices of 64 ----
  {
    const unsigned short* aS = aT + (size_t)m0 * 64;
    const unsigned short* bS = bT + (size_t)n0 * 64;
#pragma unroll
    for (int p_ = 0; p_ < 4; ++p_) {
      int ch = p_ * 8 + w;
      gld16(aS + ch * 512 + laneoff, smem + ch * 1024);
      gld16(bS + ch * 512 + laneoff, smem + 32768 + ch * 1024);
    }
  }
  __syncthreads();

  for (int kt = 0; kt < 4; ++kt) {
    if (kt < 3) {  // issue next-slice loads into the other buffer
      char* nb = smem + ((kt + 1) & 1) * 65536;
      const unsigned short* aS = aT + ((size_t)(kt + 1) * MDIM + m0) * 64;
      const unsigned short* bS = bT + ((size_t)(kt + 1) * MDIM + n0) * 64;
#pragma unroll
      for (int p_ = 0; p_ < 4; ++p_) {
        int ch = p_ * 8 + w;
        gld16(aS + ch * 512 + laneoff, nb + ch * 1024);
        gld16(bS + ch * 512 + laneoff, nb + 32768 + ch * 1024);
      }
    }
    const char* cb = smem + (kt & 1) * 65536;
    const char* cbB = cb + 32768;

#pragma unroll
    for (int ks = 0; ks < 2; ++ks) {
      const int segoff = (((ks * 4 + quad) ^ r8) << 4);
      bf16x8 af[8];
#pragma unroll
      for (int mt = 0; mt < 8; ++mt) {
        int chunk = wm * 16 + mt * 2 + (lr >> 3);
        af[mt] = *(const bf16x8*)(cb + chunk * 1024 + r8 * 128 + segoff);
      }
#pragma unroll
      for (int nt = 0; nt < 4; ++nt) {
        int chunk = wn * 8 + nt * 2 + (lr >> 3);
        bf16x8 bfr = *(const bf16x8*)(cbB + chunk * 1024 + r8 * 128 + segoff);
#pragma unroll
        for (int mt = 0; mt < 8; ++mt)
          acc[mt][nt] =
              __builtin_amdgcn_mfma_f32_16x16x32_bf16(af[mt], bfr, acc[mt][nt], 0, 0, 0);
      }
    }
    __syncthreads();  // next-tile DMA has the full compute phase to land
  }

  // ---- repack o (bf16, /256) into o_lds[64 p][1024 q'] XOR-swizzled ----
  const float scale = 1.0f / 256.0f;
#pragma unroll
  for (int mt = 0; mt < 8; ++mt) {
    int i_l = wm * 4 + (mt >> 1);
    int chc = 2 * (mt & 1) + (quad >> 1); // c0>>3, c0 = (mt&1)*16 + quad*4
#pragma unroll
    for (int nt = 0; nt < 4; ++nt) {
      int j_l = wn * 2 + (nt >> 1);
      int d = (nt & 1) * 16 + lr;
      int p = i_l * 8 + j_l;
      int ch = d * 4 + chc;
      int key = (p ^ d) & 7;
      int off = p * 2048 + ((ch ^ key) << 4) + 8 * (quad & 1);
      short4v pk;
      pk[0] = (short)f2bf(acc[mt][nt][0] * scale);
      pk[1] = (short)f2bf(acc[mt][nt][1] * scale);
      pk[2] = (short)f2bf(acc[mt][nt][2] * scale);
      pk[3] = (short)f2bf(acc[mt][nt][3] * scale);
      *(short4v*)(smem + off) = pk;
    }
  }
  __syncthreads();

  // ---- z[p][e] = sum_q' o[p][q'] * W3T ; wave w owns e-tile w (16 e) ----
  f32x4 zacc[4];
#pragma unroll
  for (int a = 0; a < 4; ++a) {
    zacc[a][0] = 0.f; zacc[a][1] = 0.f; zacc[a][2] = 0.f; zacc[a][3] = 0.f;
  }
  const float bias = b3[w * 16 + lr];

  // kq-major W3T: frag = W3T + (kq*128 + e)*32 + quad*8 ; kq step 4096 shorts
  const unsigned short* wg = W3T + (size_t)(w * 16 + lr) * 32 + quad * 8;

  bf16x8 wcur = *(const bf16x8*)(wg);
#pragma unroll
  for (int kq = 0; kq < 32; ++kq) {
    bf16x8 wnxt;
    if (kq < 31) wnxt = *(const bf16x8*)(wg + (size_t)(kq + 1) * 4096);
    bf16x8 aef[4];
#pragma unroll
    for (int mte = 0; mte < 4; ++mte) {
      int row = mte * 16 + lr;
      int ch = kq * 4 + quad;
      int key = (row ^ kq) & 7;
      aef[mte] = *(const bf16x8*)(smem + row * 2048 + ((ch ^ key) << 4));
    }
#pragma unroll
    for (int mte = 0; mte < 4; ++mte)
      zacc[mte] = __builtin_amdgcn_mfma_f32_16x16x32_bf16(aef[mte], wcur, zacc[mte], 0, 0, 0);
    wcur = wnxt;
  }

  const int i0 = by * 8, j0 = bx * 8;
  const int e = w * 16 + lr;
#pragma unroll
  for (int mte = 0; mte < 4; ++mte)
#pragma unroll
    for (int r = 0; r < 4; ++r) {
      int p = mte * 16 + quad * 4 + r;
      out[(((size_t)(i0 + (p >> 3))) * NRES + (j0 + (p & 7))) * CZ + e] =
          zacc[mte][r] + bias;
    }
}

// ---------------- host launch ----------------
extern "C" void kernel_launch(void* const* d_in, const int* in_sizes, int n_in,
                              void* d_out, int out_size, void* d_ws, size_t ws_size,
                              hipStream_t stream) {
  const float* m = (const float*)d_in[0];
  const float* gamma = (const float*)d_in[1];
  const float* beta = (const float*)d_in[2];
  const float* W1 = (const float*)d_in[3];
  const float* W2 = (const float*)d_in[4];
  const float* W3 = (const float*)d_in[5];
  const float* b3 = (const float*)d_in[6];
  float* out = (float*)d_out;

  unsigned short* aT = (unsigned short*)d_ws;                 // k-slice-major
  unsigned short* bT = aT + (size_t)MDIM * S_DEPTH;
  unsigned short* W3T = bT + (size_t)MDIM * S_DEPTH;          // kq-major

  k_pre<<<400, 256, 0, stream>>>(m, gamma, beta, W1, W2, W3, aT, bT, W3T);
  k_opm<<<2304, 512, 0, stream>>>(aT, bT, W3T, b3, out);
}